// Round 6
// baseline (197.959 us; speedup 1.0000x reference)
//
#include <hip/hip_runtime.h>
#include <stdint.h>

#define M_DIM 16384
#define N_DIM 1024
#define K_DIM 1024

#define BM 128
#define BN 128
#define BK 64
#define LDSW 20   // dwords per LDS row: 64B data + 16B pad. Frag-read banks
                  // (20*row+4*ch)%32 -> <=2-way (free); 64B rows were 8-way.

using i32x4 = __attribute__((ext_vector_type(4))) int;

__device__ __forceinline__ int pack4(int4 v) {
    return (v.x & 0xFF) | ((v.y & 0xFF) << 8) | ((v.z & 0xFF) << 16) | ((v.w & 0xFF) << 24);
}

// ------------- pack w + corr: one block per output column ----------
// corr[n] = bias[n] - 3 * sum_k w[n,k]   (weight_zp=0 -> exact fold)
__global__ __launch_bounds__(256) void pack_w_corr_kernel(const int* __restrict__ w,
                                                          const int* __restrict__ bias,
                                                          int8_t* __restrict__ wq,
                                                          int* __restrict__ corr) {
    int col = blockIdx.x;
    int t = threadIdx.x;
    int4 v = ((const int4*)(w + (size_t)col * K_DIM))[t];
    ((int*)(wq + (size_t)col * K_DIM))[t] = pack4(v);
    int s = v.x + v.y + v.z + v.w;
#pragma unroll
    for (int m = 1; m < 64; m <<= 1) s += __shfl_xor(s, m);
    __shared__ int partial[4];
    if ((t & 63) == 0) partial[t >> 6] = s;
    __syncthreads();
    if (t == 0) {
        int total = partial[0] + partial[1] + partial[2] + partial[3];
        corr[col] = bias[col] - 3 * total;
    }
}

// ---------------- fused GEMM: pack x in-register, i8 MFMA, requant ----------------
// 128x128 tile, BK=64, 4 waves (2x2 of 64x64), mfma_i32_16x16x64_i8.
// DEPTH-2 software pipeline: two load register sets rotate so the wait
// before each WRITE is a counted vmcnt (other set stays in flight) -- the
// T4 mechanism at source level. 2 LDS buffers, 1 barrier per K-step.
__global__ __launch_bounds__(256) void gemm_fused_kernel(const int* __restrict__ X,
                                                         const int8_t* __restrict__ Wq,
                                                         const int* __restrict__ corr,
                                                         int* __restrict__ out) {
    __shared__ int Asm[2][BM * LDSW];   // 2 x 10 KiB
    __shared__ int Bsm[2][BN * LDSW];

    int bid = blockIdx.x;
    // XCD-bijective swizzle (nwg=1024 % 8 == 0).
    int swz = (bid & 7) * 128 + (bid >> 3);
    int m0 = (swz >> 3) * BM;
    int n0 = (swz & 7) * BN;

    int tid = threadIdx.x;
    int lane = tid & 63;
    int wave = tid >> 6;
    int wm = wave >> 1;
    int wn = wave & 1;
    int r16 = lane & 15;
    int krow = lane >> 4;

    i32x4 acc[4][4];
#pragma unroll
    for (int i = 0; i < 4; ++i)
#pragma unroll
        for (int j = 0; j < 4; ++j)
            acc[i][j] = (i32x4){0, 0, 0, 0};

    // A staging: 8 int4 loads/thread/K-step; dword f=i*256+tid:
    //   row = i*16 + (tid>>4), dcol = tid&15 (4 rows x 256B contiguous per instr)
    int arow = tid >> 4;
    int adcol = tid & 15;
    const int* Abase = X + (size_t)(m0 + arow) * K_DIM + adcol * 4;
    // B staging (packed i8): 2 int4 loads/thread/K-step; 16B unit f=i*256+tid:
    //   row = i*64 + (tid>>2), dc4 = tid&3
    int brow = tid >> 2;
    int bdc4 = tid & 3;
    const int8_t* Bbase = Wq + (size_t)(n0 + brow) * K_DIM + bdc4 * 16;

    int4 a0[8], a1[8];
    int4 b0[2], b1[2];

#define LOADT(AR, BR, kt)                                                          \
    {                                                                              \
        _Pragma("unroll") for (int i = 0; i < 8; ++i)                              \
            AR[i] = *(const int4*)(Abase + (size_t)i * 16 * K_DIM + (kt) * BK);    \
        _Pragma("unroll") for (int i = 0; i < 2; ++i)                              \
            BR[i] = *(const int4*)(Bbase + (size_t)i * 64 * K_DIM + (kt) * BK);    \
    }

#define WRITET(buf, AR, BR)                                                        \
    {                                                                              \
        _Pragma("unroll") for (int i = 0; i < 8; ++i)                              \
            Asm[buf][(i * 16 + arow) * LDSW + adcol] = pack4(AR[i]);               \
        _Pragma("unroll") for (int i = 0; i < 2; ++i)                              \
            *(int4*)&Bsm[buf][(i * 64 + brow) * LDSW + bdc4 * 4] = BR[i];          \
    }

#define COMPUTE(buf)                                                               \
    {                                                                              \
        i32x4 afr[4], bfr[4];                                                      \
        _Pragma("unroll") for (int i = 0; i < 4; ++i) {                            \
            afr[i] = *(const i32x4*)&Asm[buf][(wm * 64 + i * 16 + r16) * LDSW + krow * 4]; \
            bfr[i] = *(const i32x4*)&Bsm[buf][(wn * 64 + i * 16 + r16) * LDSW + krow * 4]; \
        }                                                                          \
        _Pragma("unroll") for (int i = 0; i < 4; ++i)                              \
            _Pragma("unroll") for (int j = 0; j < 4; ++j)                          \
                acc[i][j] = __builtin_amdgcn_mfma_i32_16x16x64_i8(afr[i], bfr[j], acc[i][j], 0, 0, 0); \
    }

    // Prologue: steps 0 and 1 in flight; publish step 0.
    LOADT(a0, b0, 0);
    LOADT(a1, b1, 1);
    WRITET(0, a0, b0);          // waits set0 only (set1 stays outstanding)
    __syncthreads();

    for (int kt = 0; kt < K_DIM / BK; kt += 2) {
        // even: compute buf0(step kt); publish buf1(step kt+1); prefetch kt+2
        if (kt + 2 < 16) LOADT(a0, b0, kt + 2);
        COMPUTE(0);
        WRITET(1, a1, b1);      // counted wait: set0's 10 loads stay in flight
        __syncthreads();
        // odd: compute buf1(step kt+1); publish buf0(step kt+2); prefetch kt+3
        if (kt + 3 < 16) LOADT(a1, b1, kt + 3);
        COMPUTE(1);
        if (kt + 2 < 16) {
            WRITET(0, a0, b0);  // counted wait: set1 stays in flight
        }
        __syncthreads();
    }

    // Epilogue: C/D layout col = lane&15, row = (lane>>4)*4 + reg.
    int col16 = lane & 15;
    int rbase = (lane >> 4) * 4;
#pragma unroll
    for (int j = 0; j < 4; ++j) {
        int c = n0 + wn * 64 + j * 16 + col16;
        int cr = corr[c];
#pragma unroll
        for (int i = 0; i < 4; ++i) {
            int rrow = m0 + wm * 64 + i * 16 + rbase;
#pragma unroll
            for (int r = 0; r < 4; ++r) {
                int t = acc[i][j][r] + cr;
                int res = ((t * 10) >> 10) - 5;       // floor((acc*10)/1024) + OUTPUT_ZP
                res = res < -128 ? -128 : (res > 127 ? 127 : res);
                out[(size_t)(rrow + r) * N_DIM + c] = res;
            }
        }
    }
#undef LOADT
#undef WRITET
#undef COMPUTE
}

extern "C" void kernel_launch(void* const* d_in, const int* in_sizes, int n_in,
                              void* d_out, int out_size, void* d_ws, size_t ws_size,
                              hipStream_t stream) {
    (void)in_sizes; (void)n_in; (void)out_size; (void)ws_size;
    const int* x    = (const int*)d_in[0];
    const int* w    = (const int*)d_in[1];
    const int* bias = (const int*)d_in[2];
    int* out = (int*)d_out;

    int8_t* wq = (int8_t*)d_ws;                          // 1 MiB
    int* corr  = (int*)(wq + (size_t)N_DIM * K_DIM);     // 4 KiB

    pack_w_corr_kernel<<<N_DIM, 256, 0, stream>>>(w, bias, wq, corr);
    gemm_fused_kernel<<<(M_DIM / BM) * (N_DIM / BN), 256, 0, stream>>>(x, wq, corr, out);
}

// Round 8
// 136.376 us; speedup vs baseline: 1.4516x; 1.4516x over previous
//
#include <hip/hip_runtime.h>
#include <stdint.h>

#define M_DIM 16384
#define N_DIM 1024
#define K_DIM 1024

#define BM 128
#define BN 128
#define BK 64
#define NKT (K_DIM / BK)          // 16 K-steps
#define TILE_BYTES (BM * BK)      // 8192 B per (tile, K-step)

using i32x4 = __attribute__((ext_vector_type(4))) int;

__device__ __forceinline__ int pack4(int4 v) {
    return (v.x & 0xFF) | ((v.y & 0xFF) << 8) | ((v.z & 0xFF) << 16) | ((v.w & 0xFF) << 24);
}

// Swizzle: within each row's 64B (4 slots of 16B), canonical slot sigma is
// stored at s = sigma ^ ((row>>1)&3). Involution, within one 64B line ->
// global coalescing unaffected; kills the 8-way ds_read_b128 conflict
// (16 lanes/krow-group -> 8 distinct 4-bank starts x2 = 2-way = free).

// -------- pack x: int32 [M,K] -> swizzled-tiled i8 xqT[mtile][kt][512*16B] --------
// grid = 128 mtiles * 16 kts = 2048 blocks. Reads coalesced (j*16 strided
// within 256B row-regions, L1 completes lines); writes line-coalesced.
__global__ __launch_bounds__(256) void pack_x_kernel(const int* __restrict__ X,
                                                     int8_t* __restrict__ xqT) {
    int mtile = blockIdx.x >> 4;
    int kt = blockIdx.x & 15;
    int8_t* outT = xqT + (size_t)blockIdx.x * TILE_BYTES;
    int tid = threadIdx.x;
#pragma unroll
    for (int i = 0; i < 2; ++i) {
        int c = i * 256 + tid;          // input chunk: row = c>>2, sigma = c&3
        int row = c >> 2;
        int sig = c & 3;
        const int* src = X + ((size_t)(mtile * BM + row)) * K_DIM + kt * BK + sig * 16;
        int4 p;
        p.x = pack4(*(const int4*)(src + 0));
        p.y = pack4(*(const int4*)(src + 4));
        p.z = pack4(*(const int4*)(src + 8));
        p.w = pack4(*(const int4*)(src + 12));
        int s = sig ^ ((row >> 1) & 3);           // swizzled slot
        *(int4*)(outT + ((size_t)row * 4 + s) * 16) = p;
    }
}

// ---- pack w + corr: wqT[ntile][kt][512*16B] swizzled; corr[n] = bias - 3*colsum ----
// grid = 1024 blocks (one per output column n), 256 threads (4 ints each).
__global__ __launch_bounds__(256) void pack_w_corr_kernel(const int* __restrict__ w,
                                                          const int* __restrict__ bias,
                                                          int8_t* __restrict__ wqT,
                                                          int* __restrict__ corr) {
    int n = blockIdx.x;
    int t = threadIdx.x;
    int4 v = ((const int4*)(w + (size_t)n * K_DIM))[t];
    int pk = pack4(v);
    int kt = t >> 4;                 // 64 ints per kt
    int sig = (t >> 2) & 3;          // canonical 16B slot within the row's 64B
    int d = t & 3;                   // dword within slot
    int rowin = n & 127;
    int ntile = n >> 7;
    int s = sig ^ ((rowin >> 1) & 3);
    ((int*)(wqT + ((size_t)(ntile * NKT + kt)) * TILE_BYTES))[(rowin * 4 + s) * 4 + d] = pk;

    int sum = v.x + v.y + v.z + v.w;
#pragma unroll
    for (int m = 1; m < 64; m <<= 1) sum += __shfl_xor(sum, m);
    __shared__ int partial[4];
    if ((t & 63) == 0) partial[t >> 6] = sum;
    __syncthreads();
    if (t == 0)
        corr[n] = bias[n] - 3 * (partial[0] + partial[1] + partial[2] + partial[3]);
}

// ---------------- GEMM: m97 structure, global_load_lds, swizzled reads ----------------
// 128x128 tile, BK=64, 4 waves (2x2 of 64x64), mfma_i32_16x16x64_i8.
// LDS 16 KB single-buffered, 2 barriers/K-step; tiles are contiguous 8 KB.
__global__ __launch_bounds__(256) void gemm_kernel(const int8_t* __restrict__ xqT,
                                                   const int8_t* __restrict__ wqT,
                                                   const int* __restrict__ corr,
                                                   int* __restrict__ out) {
    __shared__ int8_t Asm[TILE_BYTES];
    __shared__ int8_t Bsm[TILE_BYTES];

    int bid = blockIdx.x;
    // XCD-bijective swizzle (nwg=1024 % 8 == 0).
    int swz = (bid & 7) * 128 + (bid >> 3);
    int mtile = swz >> 3;    // 0..127
    int ntile = swz & 7;     // 0..7
    int n0 = ntile * BN;

    int tid = threadIdx.x;
    int lane = tid & 63;
    int wave = tid >> 6;
    int wm = wave >> 1;
    int wn = wave & 1;
    int r16 = lane & 15;
    int krow = lane >> 4;                 // canonical k-slot
    int slot = krow ^ ((r16 >> 1) & 3);   // swizzled LDS slot (row>>1 &3 == r16>>1 &3)

    i32x4 acc[4][4];
#pragma unroll
    for (int i = 0; i < 4; ++i)
#pragma unroll
        for (int j = 0; j < 4; ++j)
            acc[i][j] = (i32x4){0, 0, 0, 0};

    const int8_t* Abase = xqT + (size_t)mtile * NKT * TILE_BYTES;
    const int8_t* Bbase = wqT + (size_t)ntile * NKT * TILE_BYTES;

    for (int kt = 0; kt < NKT; ++kt) {
        const int8_t* Ag = Abase + (size_t)kt * TILE_BYTES;
        const int8_t* Bg = Bbase + (size_t)kt * TILE_BYTES;
        // Stage 8 KB + 8 KB: 2+2 x 16B per thread, perfectly sequential.
#pragma unroll
        for (int i = 0; i < 2; ++i) {
            int f = i * 256 + tid;
            __builtin_amdgcn_global_load_lds(
                (const __attribute__((address_space(1))) unsigned int*)(Ag + (size_t)f * 16),
                (__attribute__((address_space(3))) unsigned int*)(Asm + f * 16),
                16, 0, 0);
        }
#pragma unroll
        for (int i = 0; i < 2; ++i) {
            int f = i * 256 + tid;
            __builtin_amdgcn_global_load_lds(
                (const __attribute__((address_space(1))) unsigned int*)(Bg + (size_t)f * 16),
                (__attribute__((address_space(3))) unsigned int*)(Bsm + f * 16),
                16, 0, 0);
        }
        __syncthreads();

        i32x4 afr[4], bfr[4];
#pragma unroll
        for (int i = 0; i < 4; ++i) {
            afr[i] = *(const i32x4*)(Asm + (size_t)(wm * 64 + i * 16 + r16) * 64 + slot * 16);
            bfr[i] = *(const i32x4*)(Bsm + (size_t)(wn * 64 + i * 16 + r16) * 64 + slot * 16);
        }
#pragma unroll
        for (int i = 0; i < 4; ++i)
#pragma unroll
            for (int j = 0; j < 4; ++j)
                acc[i][j] = __builtin_amdgcn_mfma_i32_16x16x64_i8(afr[i], bfr[j], acc[i][j], 0, 0, 0);
        __syncthreads();
    }

    // Epilogue: C/D layout col = lane&15, row = (lane>>4)*4 + reg.
    int m0 = mtile * BM;
    int col16 = lane & 15;
    int rbase = (lane >> 4) * 4;
#pragma unroll
    for (int j = 0; j < 4; ++j) {
        int c = n0 + wn * 64 + j * 16 + col16;
        int cr = corr[c];
#pragma unroll
        for (int i = 0; i < 4; ++i) {
            int rrow = m0 + wm * 64 + i * 16 + rbase;
#pragma unroll
            for (int r = 0; r < 4; ++r) {
                int t = acc[i][j][r] + cr;
                int res = ((t * 10) >> 10) - 5;       // floor((acc*10)/1024) + OUTPUT_ZP
                res = res < -128 ? -128 : (res > 127 ? 127 : res);
                out[(size_t)(rrow + r) * N_DIM + c] = res;
            }
        }
    }
}

extern "C" void kernel_launch(void* const* d_in, const int* in_sizes, int n_in,
                              void* d_out, int out_size, void* d_ws, size_t ws_size,
                              hipStream_t stream) {
    (void)in_sizes; (void)n_in; (void)out_size; (void)ws_size;
    const int* x    = (const int*)d_in[0];
    const int* w    = (const int*)d_in[1];
    const int* bias = (const int*)d_in[2];
    int* out = (int*)d_out;

    int8_t* xqT = (int8_t*)d_ws;                               // 16 MiB (tiled+swizzled)
    int8_t* wqT = xqT + (size_t)M_DIM * K_DIM;                 // 1 MiB (tiled+swizzled)
    int* corr   = (int*)(wqT + (size_t)N_DIM * K_DIM);         // 4 KiB

    pack_x_kernel<<<(M_DIM / BM) * NKT, 256, 0, stream>>>(x, xqT);
    pack_w_corr_kernel<<<N_DIM, 256, 0, stream>>>(w, bias, wqT, corr);
    gemm_kernel<<<(M_DIM / BM) * (N_DIM / BN), 256, 0, stream>>>(xqT, wqT, corr, out);
}